// Round 2
// baseline (1067.533 us; speedup 1.0000x reference)
//
#include <hip/hip_runtime.h>

// NLBlockND non-local block, fp16-MFMA implementation (fp16 chosen over bf16:
// scores sigma~22.6 make softmax precision-critical; fp16's 2^-11 roundoff
// keeps score jitter ~0.01 vs bf16's ~0.1).
// Pipeline: cvt weights -> transpose x1/x2 to fp16 (B*N,C) -> 3 proj GEMMs
// (g stored transposed) -> flash attention (online softmax) -> wz GEMM +
// BN stats atomics -> BN finalize -> normalize+residual+transpose out.

typedef _Float16 half8 __attribute__((ext_vector_type(8)));
typedef float floatx4 __attribute__((ext_vector_type(4)));

constexpr int B_ = 8, C_ = 1024, CI_ = 512, N_ = 3136;
constexpr int M_ = B_ * N_;            // 25088 rows (batch-major, n within batch)
constexpr float BN_EPS = 1e-5f;

// workspace layout (bytes, all 256-aligned)
constexpr size_t XT1_OFF = 0;
constexpr size_t XT2_OFF = XT1_OFF + (size_t)M_ * C_ * 2;
constexpr size_t WTH_OFF = XT2_OFF + (size_t)M_ * C_ * 2;
constexpr size_t WPH_OFF = WTH_OFF + (size_t)CI_ * C_ * 2;
constexpr size_t WG_OFF  = WPH_OFF + (size_t)CI_ * C_ * 2;
constexpr size_t WZB_OFF = WG_OFF  + (size_t)CI_ * C_ * 2;
constexpr size_t TH_OFF  = WZB_OFF + (size_t)C_ * CI_ * 2;
constexpr size_t PH_OFF  = TH_OFF  + (size_t)M_ * CI_ * 2;
constexpr size_t GXT_OFF = PH_OFF  + (size_t)M_ * CI_ * 2;
constexpr size_t Y_OFF   = GXT_OFF + (size_t)M_ * CI_ * 2;
constexpr size_t WY_OFF  = Y_OFF   + (size_t)M_ * CI_ * 2;   // fp16 wy
constexpr size_t SSUM_OFF= WY_OFF  + (size_t)M_ * C_ * 2;
constexpr size_t SSQ_OFF = SSUM_OFF + 4096;
constexpr size_t SC_OFF  = SSQ_OFF + 4096;                    // scale[1024], shift[1024]

__device__ __forceinline__ ushort f2h(float f) {
    _Float16 h = (_Float16)f;
    union { _Float16 h; ushort u; } v; v.h = h;
    return v.u;
}
__device__ __forceinline__ float h2f(ushort u) {
    union { ushort u; _Float16 h; } v; v.u = u;
    return (float)v.h;
}

// ---- weight convert: 4 arrays of 524288 floats -> fp16 -------------------
__global__ __launch_bounds__(256) void cvtw4(const float* __restrict__ a, const float* __restrict__ b,
                                             const float* __restrict__ c, const float* __restrict__ d,
                                             ushort* oa, ushort* ob, ushort* oc, ushort* od) {
    const float* s; ushort* o;
    switch (blockIdx.y) {
        case 0: s = a; o = oa; break;
        case 1: s = b; o = ob; break;
        case 2: s = c; o = oc; break;
        default: s = d; o = od; break;
    }
    int i = (blockIdx.x * 256 + threadIdx.x) * 4;
    float4 v = *(const float4*)&s[i];
    ushort4 u; u.x = f2h(v.x); u.y = f2h(v.y); u.z = f2h(v.z); u.w = f2h(v.w);
    *(ushort4*)&o[i] = u;
}

// ---- transpose x (B,C,N) fp32 -> xt (B*N, C) fp16 ------------------------
__global__ __launch_bounds__(256) void xpose(const float* __restrict__ x, ushort* __restrict__ xt) {
    __shared__ ushort T[64 * 68];
    const int b = blockIdx.z, n0 = blockIdx.y * 64, c0 = blockIdx.x * 64;
    const int t = threadIdx.x;
    {
        const int cl = t >> 4, jb = (t & 15) * 4;
        #pragma unroll
        for (int i = 0; i < 4; ++i) {
            int c = cl + i * 16;
            float4 v = *(const float4*)&x[((size_t)b * C_ + c0 + c) * N_ + n0 + jb];
            ushort4 u; u.x = f2h(v.x); u.y = f2h(v.y); u.z = f2h(v.z); u.w = f2h(v.w);
            *(ushort4*)&T[c * 68 + jb] = u;
        }
    }
    __syncthreads();
    {
        const int nl = t >> 4, cb = (t & 15) * 4;
        #pragma unroll
        for (int i = 0; i < 4; ++i) {
            int n = nl + i * 16;
            ushort4 u;
            u.x = T[(cb + 0) * 68 + n];
            u.y = T[(cb + 1) * 68 + n];
            u.z = T[(cb + 2) * 68 + n];
            u.w = T[(cb + 3) * 68 + n];
            *(ushort4*)&xt[((size_t)b * N_ + n0 + n) * C_ + c0 + cb] = u;
        }
    }
}

// ---- generic 128x128 fp16 MFMA GEMM: out = A(MxK) * Bt(NOUTxK)^T + bias --
// MODE 0: fp16 out row-major (stride NOUT)
// MODE 1: fp16 out transposed per-batch: GXT[b][col][n]  (NOUT==CI_)
// MODE 2: fp16 out row-major + per-col sum/sumsq atomics (BN stats)
template<int K, int NOUT, int MODE>
__global__ __launch_bounds__(256, 2) void gemm_bt(
    const ushort* __restrict__ A, const ushort* __restrict__ Bt,
    const float* __restrict__ bias, ushort* __restrict__ outb,
    float* __restrict__ ssum, float* __restrict__ ssq)
{
    __shared__ ushort Als[128 * 40];
    __shared__ ushort Bls[128 * 40];
    const int t = threadIdx.x;
    const int w = t >> 6, l = t & 63, quad = l >> 4, lid = l & 15;
    const int rw = w & 1, cw = w >> 1;
    const int rowbase = blockIdx.y * 128, colbase = blockIdx.x * 128;

    floatx4 acc[4][4] = {};

    for (int ks = 0; ks < K / 32; ++ks) {
        __syncthreads();
        #pragma unroll
        for (int i = 0; i < 2; ++i) {
            int idx = t + i * 256;
            int row = idx >> 2, ch = idx & 3;
            *(uint4*)&Als[row * 40 + ch * 8] =
                *(const uint4*)&A[(size_t)(rowbase + row) * K + ks * 32 + ch * 8];
            *(uint4*)&Bls[row * 40 + ch * 8] =
                *(const uint4*)&Bt[(size_t)(colbase + row) * K + ks * 32 + ch * 8];
        }
        __syncthreads();
        half8 af[4];
        #pragma unroll
        for (int rt = 0; rt < 4; ++rt)
            af[rt] = *(const half8*)&Als[(rw * 64 + rt * 16 + lid) * 40 + quad * 8];
        #pragma unroll
        for (int ct = 0; ct < 4; ++ct) {
            half8 bf = *(const half8*)&Bls[(cw * 64 + ct * 16 + lid) * 40 + quad * 8];
            #pragma unroll
            for (int rt = 0; rt < 4; ++rt)
                acc[rt][ct] = __builtin_amdgcn_mfma_f32_16x16x32_f16(af[rt], bf, acc[rt][ct], 0, 0, 0);
        }
    }

    #pragma unroll
    for (int ct = 0; ct < 4; ++ct) {
        const int col = colbase + cw * 64 + ct * 16 + lid;
        const float bv = bias[col];
        float s = 0.f, q = 0.f;
        #pragma unroll
        for (int rt = 0; rt < 4; ++rt) {
            const int row0 = rowbase + rw * 64 + rt * 16 + quad * 4;
            if constexpr (MODE == 1) {
                const int bb = row0 / N_;
                const int nn = row0 - bb * N_;
                ushort4 u;
                u.x = f2h(acc[rt][ct][0] + bv);
                u.y = f2h(acc[rt][ct][1] + bv);
                u.z = f2h(acc[rt][ct][2] + bv);
                u.w = f2h(acc[rt][ct][3] + bv);
                *(ushort4*)&outb[((size_t)bb * CI_ + col) * N_ + nn] = u;
            } else {
                #pragma unroll
                for (int r = 0; r < 4; ++r) {
                    float v = acc[rt][ct][r] + bv;
                    outb[(size_t)(row0 + r) * NOUT + col] = f2h(v);
                    if constexpr (MODE == 2) { s += v; q += v * v; }
                }
            }
        }
        if constexpr (MODE == 2) {
            s += __shfl_xor(s, 16, 64); s += __shfl_xor(s, 32, 64);
            q += __shfl_xor(q, 16, 64); q += __shfl_xor(q, 32, 64);
            if (quad == 0) {
                atomicAdd(&ssum[col], s);
                atomicAdd(&ssq[col], q);
            }
        }
    }
}

// ---- flash attention: per block one (batch, 64-row q-tile) ---------------
// TH fragments register-cached; PH / GX^T streamed through one LDS buffer.
__global__ __launch_bounds__(512, 2) void attn(
    const ushort* __restrict__ TH, const ushort* __restrict__ PH,
    const ushort* __restrict__ GXT, ushort* __restrict__ Y)
{
    __shared__ ushort STR[20480];          // PH tile [32][520] or GX^T tile [512][40]
    __shared__ float  Ss[64 * 33];
    __shared__ ushort Ps[64 * 40];
    __shared__ float  mrow[64], lrow[64], arow[64];
    __shared__ float  red[64 * 8];

    const int t = threadIdx.x;
    const int w = t >> 6, l = t & 63, quad = l >> 4, lid = l & 15;
    const int rw = w & 3;                  // row group (16 rows) for S and O
    const int dh = w >> 2;                 // d half (256 cols) for O
    const int b = blockIdx.x / 49, q = blockIdx.x % 49;
    const int n0 = q * 64;
    const int srow = t >> 3, sj = t & 7;   // softmax: 8 threads per row

    // register-cache TH rows for this wave: rows n0 + rw*16 + lid, all 512 k
    half8 thr[16];
    {
        const size_t baseTH = ((size_t)b * N_ + n0 + rw * 16 + lid) * CI_;
        #pragma unroll
        for (int kc = 0; kc < 16; ++kc)
            thr[kc] = *(const half8*)&TH[baseTH + kc * 32 + quad * 8];
    }
    if (t < 64) { mrow[t] = -1e30f; lrow[t] = 0.f; }
    floatx4 acc[16] = {};

    for (int s = 0; s < N_ / 32; ++s) {
        const int m0 = s * 32;
        __syncthreads();                                   // (a) O-phase done with STR/Ps
        {   // stage PH tile 32x512
            const size_t basePH = ((size_t)b * N_ + m0) * CI_;
            #pragma unroll
            for (int i = 0; i < 4; ++i) {
                int idx = t + i * 512;
                int row = idx >> 6, ch = idx & 63;
                *(uint4*)&STR[row * 520 + ch * 8] =
                    *(const uint4*)&PH[basePH + (size_t)row * CI_ + ch * 8];
            }
        }
        __syncthreads();                                   // (b) PH visible
        {   // S = TH * PH^T : wave computes tile (rw, ct=dh)
            floatx4 sacc = {};
            #pragma unroll
            for (int ks = 0; ks < 16; ++ks) {
                half8 bb = *(const half8*)&STR[(dh * 16 + lid) * 520 + ks * 32 + quad * 8];
                sacc = __builtin_amdgcn_mfma_f32_16x16x32_f16(thr[ks], bb, sacc, 0, 0, 0);
            }
            const int col = dh * 16 + lid;
            #pragma unroll
            for (int r = 0; r < 4; ++r)
                Ss[(rw * 16 + quad * 4 + r) * 33 + col] = sacc[r];
        }
        __syncthreads();                                   // (c) Ss visible, STR free
        {   // stage GX^T tile 512x32 (overlaps softmax below)
            const size_t baseGX = (size_t)b * CI_ * N_ + m0;
            #pragma unroll
            for (int i = 0; i < 4; ++i) {
                int idx = t + i * 512;
                int d = idx >> 2, ch = idx & 3;
                *(uint4*)&STR[d * 40 + ch * 8] =
                    *(const uint4*)&GXT[baseGX + (size_t)d * N_ + ch * 8];
            }
        }
        {   // partial max over this step's 32 cols
            float pm = Ss[srow * 33 + sj * 4];
            pm = fmaxf(pm, Ss[srow * 33 + sj * 4 + 1]);
            pm = fmaxf(pm, Ss[srow * 33 + sj * 4 + 2]);
            pm = fmaxf(pm, Ss[srow * 33 + sj * 4 + 3]);
            red[srow * 8 + sj] = pm;
        }
        __syncthreads();                                   // (d) red + GX visible
        if (sj == 0) {
            float m_ = red[srow * 8];
            #pragma unroll
            for (int k = 1; k < 8; ++k) m_ = fmaxf(m_, red[srow * 8 + k]);
            const float mo = mrow[srow];
            const float mn = fmaxf(mo, m_);
            mrow[srow] = mn;
            arow[srow] = __expf(mo - mn);
        }
        __syncthreads();                                   // (e) mrow/arow visible
        {   // P = exp(S - m), partial row sums
            const float mn = mrow[srow];
            float ps = 0.f;
            #pragma unroll
            for (int k = 0; k < 4; ++k) {
                float p = __expf(Ss[srow * 33 + sj * 4 + k] - mn);
                Ps[srow * 40 + sj * 4 + k] = f2h(p);
                ps += p;
            }
            red[srow * 8 + sj] = ps;
        }
        {   // rescale O by alpha
            float al[4];
            #pragma unroll
            for (int r = 0; r < 4; ++r) al[r] = arow[rw * 16 + quad * 4 + r];
            #pragma unroll
            for (int ctl = 0; ctl < 16; ++ctl)
                #pragma unroll
                for (int r = 0; r < 4; ++r) acc[ctl][r] *= al[r];
        }
        __syncthreads();                                   // (f) Ps/red visible
        if (sj == 0) {
            float sm = 0.f;
            #pragma unroll
            for (int k = 0; k < 8; ++k) sm += red[srow * 8 + k];
            lrow[srow] = lrow[srow] * arow[srow] + sm;
        }
        {   // O += P * GX
            half8 a = *(const half8*)&Ps[(rw * 16 + lid) * 40 + quad * 8];
            #pragma unroll
            for (int ctl = 0; ctl < 16; ++ctl) {
                half8 bb = *(const half8*)&STR[(dh * 256 + ctl * 16 + lid) * 40 + quad * 8];
                acc[ctl] = __builtin_amdgcn_mfma_f32_16x16x32_f16(a, bb, acc[ctl], 0, 0, 0);
            }
        }
    }
    __syncthreads();
    float inv[4];
    #pragma unroll
    for (int r = 0; r < 4; ++r) inv[r] = 1.0f / lrow[rw * 16 + quad * 4 + r];
    const size_t baseY = ((size_t)b * N_ + n0) * CI_;
    #pragma unroll
    for (int ctl = 0; ctl < 16; ++ctl) {
        const int col = dh * 256 + ctl * 16 + lid;
        #pragma unroll
        for (int r = 0; r < 4; ++r) {
            const int row = rw * 16 + quad * 4 + r;
            Y[baseY + (size_t)row * CI_ + col] = f2h(acc[ctl][r] * inv[r]);
        }
    }
}

// ---- BN finalize: scale/shift per channel --------------------------------
__global__ __launch_bounds__(256) void bnfin(const float* __restrict__ ssum, const float* __restrict__ ssq,
                                             const float* __restrict__ gamma, const float* __restrict__ beta,
                                             float* __restrict__ sc) {
    const int c = blockIdx.x * 256 + threadIdx.x;
    const float inv_m = 1.0f / (float)M_;
    const float mu = ssum[c] * inv_m;
    const float var = ssq[c] * inv_m - mu * mu;
    const float s = gamma[c] * rsqrtf(var + BN_EPS);
    sc[c] = s;
    sc[C_ + c] = beta[c] - mu * s;
}

// ---- finalize: out[b][c][n] = wy[b][n][c]*scale+shift + x1[b][c][n] ------
__global__ __launch_bounds__(256) void fin(const ushort* __restrict__ wy, const float* __restrict__ x1,
                                           const float* __restrict__ sc, float* __restrict__ out) {
    __shared__ float T[64 * 65];
    const int b = blockIdx.z, n0 = blockIdx.y * 64, c0 = blockIdx.x * 64;
    const int t = threadIdx.x;
    {
        const int nl = t >> 4, cb = (t & 15) * 4;
        #pragma unroll
        for (int i = 0; i < 4; ++i) {
            int n = nl + i * 16;
            ushort4 u = *(const ushort4*)&wy[((size_t)b * N_ + n0 + n) * C_ + c0 + cb];
            T[(cb + 0) * 65 + n] = h2f(u.x);
            T[(cb + 1) * 65 + n] = h2f(u.y);
            T[(cb + 2) * 65 + n] = h2f(u.z);
            T[(cb + 3) * 65 + n] = h2f(u.w);
        }
    }
    __syncthreads();
    {
        const int cl = t >> 4, nb = (t & 15) * 4;
        #pragma unroll
        for (int i = 0; i < 4; ++i) {
            int c = cl + i * 16;
            const float scale = sc[c0 + c], shift = sc[C_ + c0 + c];
            float4 xv = *(const float4*)&x1[((size_t)b * C_ + c0 + c) * N_ + n0 + nb];
            float4 o;
            o.x = T[c * 65 + nb + 0] * scale + shift + xv.x;
            o.y = T[c * 65 + nb + 1] * scale + shift + xv.y;
            o.z = T[c * 65 + nb + 2] * scale + shift + xv.z;
            o.w = T[c * 65 + nb + 3] * scale + shift + xv.w;
            *(float4*)&out[((size_t)b * C_ + c0 + c) * N_ + n0 + nb] = o;
        }
    }
}

extern "C" void kernel_launch(void* const* d_in, const int* in_sizes, int n_in,
                              void* d_out, int out_size, void* d_ws, size_t ws_size,
                              hipStream_t stream) {
    const float* x1      = (const float*)d_in[0];
    const float* x2      = (const float*)d_in[1];
    const float* g_w     = (const float*)d_in[2];
    const float* g_b     = (const float*)d_in[3];
    const float* theta_w = (const float*)d_in[4];
    const float* theta_b = (const float*)d_in[5];
    const float* phi_w   = (const float*)d_in[6];
    const float* phi_b   = (const float*)d_in[7];
    const float* wz_w    = (const float*)d_in[8];
    const float* wz_b    = (const float*)d_in[9];
    const float* bn_g    = (const float*)d_in[10];
    const float* bn_b    = (const float*)d_in[11];
    float* out = (float*)d_out;

    char* ws = (char*)d_ws;
    ushort* XT1 = (ushort*)(ws + XT1_OFF);
    ushort* XT2 = (ushort*)(ws + XT2_OFF);
    ushort* WTH = (ushort*)(ws + WTH_OFF);
    ushort* WPH = (ushort*)(ws + WPH_OFF);
    ushort* WG  = (ushort*)(ws + WG_OFF);
    ushort* WZB = (ushort*)(ws + WZB_OFF);
    ushort* THp = (ushort*)(ws + TH_OFF);
    ushort* PHp = (ushort*)(ws + PH_OFF);
    ushort* GXTp= (ushort*)(ws + GXT_OFF);
    ushort* Yp  = (ushort*)(ws + Y_OFF);
    ushort* WYp = (ushort*)(ws + WY_OFF);
    float* ssum = (float*)(ws + SSUM_OFF);
    float* ssq  = (float*)(ws + SSQ_OFF);
    float* sc   = (float*)(ws + SC_OFF);

    hipMemsetAsync(ws + SSUM_OFF, 0, 8192, stream);

    cvtw4<<<dim3(512, 4), 256, 0, stream>>>(theta_w, phi_w, g_w, wz_w, WTH, WPH, WG, WZB);
    xpose<<<dim3(16, 49, 8), 256, 0, stream>>>(x1, XT1);
    xpose<<<dim3(16, 49, 8), 256, 0, stream>>>(x2, XT2);

    gemm_bt<1024, 512, 0><<<dim3(4, 196), 256, 0, stream>>>(XT1, WTH, theta_b, THp, nullptr, nullptr);
    gemm_bt<1024, 512, 0><<<dim3(4, 196), 256, 0, stream>>>(XT2, WPH, phi_b, PHp, nullptr, nullptr);
    gemm_bt<1024, 512, 1><<<dim3(4, 196), 256, 0, stream>>>(XT2, WG, g_b, GXTp, nullptr, nullptr);

    attn<<<dim3(B_ * 49), 512, 0, stream>>>(THp, PHp, GXTp, Yp);

    gemm_bt<512, 1024, 2><<<dim3(8, 196), 256, 0, stream>>>(Yp, WZB, wz_b, WYp, ssum, ssq);
    bnfin<<<dim3(4), 256, 0, stream>>>(ssum, ssq, bn_g, bn_b, sc);
    fin<<<dim3(16, 49, 8), 256, 0, stream>>>(WYp, x1, sc, out);
}